// Round 7
// baseline (62.059 us; speedup 1.0000x reference)
//
#include <hip/hip_runtime.h>
#include <hip/hip_bf16.h>

#define B_ 64
#define S_ 128
#define D_ 1024
#define O_ 1024
#define L_ 16

typedef __bf16 bf16x8 __attribute__((ext_vector_type(8)));
typedef float f32x4 __attribute__((ext_vector_type(4)));
typedef unsigned u32x4 __attribute__((ext_vector_type(4)));

// ws layout (bytes):
//  [0, 33554432)        W bf16, tiles [l][nt:8][kt:16], each 128(o) x 64(k) bf16 = 16384 B, XOR-swizzled
//  [33554432, 50331648) x bf16, tiles [s:128][kt:16], each 64(b) x 64(k) bf16 = 8192 B, XOR-swizzled
//  [50331648]           npairs (int, 16-byte slot)
//  [50331664, +72*16)   pairs int4 {s0, s1, layer, 0}
#define WS_W   0ull
#define WS_X   33554432ull
#define WS_P   50331648ull
#define WS_NEED (50331664ull + 72ull * 16ull)

__device__ __forceinline__ unsigned f2bf2(float a, float b) {
    union { float f; unsigned u; } x{a}, y{b};
    unsigned lo = x.u + 0x7FFFu + ((x.u >> 16) & 1u);
    unsigned hi = y.u + 0x7FFFu + ((y.u >> 16) & 1u);
    return (lo >> 16) | (hi & 0xFFFF0000u);
}

__device__ __forceinline__ void gload16(const void* g, void* l) {
    __builtin_amdgcn_global_load_lds(
        (const __attribute__((address_space(1))) void*)g,
        (__attribute__((address_space(3))) void*)l, 16, 0, 0);
}

// ---- pass 1: fp32 -> bf16 conversion, OUTPUT-LINEAR mapping.
// Each thread owns 64 contiguous dest bytes (one wave = 4 KB dense stores).
// Source: the matching 128 B block of the fp32 row, piece-permuted by the
// XOR swizzle key k=(row&7)<<4. Piece loop uses STATIC register indices
// (runtime only in the store address) to avoid scratch (rule #20).
// Swizzle identity: dest(row, col^k) = src(row, col); for 64-aligned dest
// chunk c, src block = c ^ (k&64) (128B of floats); piece m in {0,16,32,48}
// (bf16 bytes) lands at dest-in-row (c^(k&64) | m) ^ k.
__global__ __launch_bounds__(256) void moshi_convert(
    const float* __restrict__ x, const float* __restrict__ w,
    const int* __restrict__ lidx, unsigned char* __restrict__ ws) {
    if (blockIdx.x == 0 && threadIdx.x < 16) {
        int t = threadIdx.x;
        int cnt[16];
        #pragma unroll 1
        for (int m = 0; m < 16; ++m) cnt[m] = 0;
        for (int s = 0; s < S_; ++s) ++cnt[lidx[s]];
        int off = 0;
        for (int m = 0; m < t; ++m) off += (cnt[m] + 1) >> 1;
        int4* pairs = (int4*)(ws + WS_P + 16);
        int k = 0, prev = -1;
        for (int s = 0; s < S_; ++s) {
            if (lidx[s] == t) {
                if (k & 1) pairs[off + (k >> 1)] = make_int4(prev, s, t, 0);
                prev = s; ++k;
            }
        }
        if (k & 1) pairs[off + (k >> 1)] = make_int4(prev, prev, t, 0);
        if (t == 0) {
            int tot = 0;
            for (int m = 0; m < 16; ++m) tot += (cnt[m] + 1) >> 1;
            *(int*)(ws + WS_P) = tot;
        }
    }

    const unsigned tid64 = blockIdx.x * 256 + threadIdx.x;   // 786432 threads total
    const unsigned beta = tid64 * 64;                        // dest byte (absolute in ws)
    const float* srcF;
    unsigned rowBase, key;
    if (beta < (unsigned)WS_X) {
        // W region: tile 16384 B = 128 rows x 128 B
        unsigned tau = beta >> 14;                 // l*128 + nt*16 + kt
        unsigned inT = beta & 16383u;
        unsigned row = inT >> 7;
        unsigned c   = inT & 127u;                 // 0 or 64
        unsigned l   = tau >> 7, nt = (tau >> 4) & 7u, kt = tau & 15u;
        key = (row & 7u) << 4;
        unsigned baseBf = c ^ (key & 64u);
        srcF = w + (size_t)((l * 1024u + nt * 128u + row)) * 1024u
                 + kt * 64u + (baseBf >> 1);
        rowBase = beta - c;
    } else {
        // x region: tile 8192 B = 64 rows x 128 B
        unsigned gamma = beta - (unsigned)WS_X;
        unsigned tau = gamma >> 13;                // s*16 + kt
        unsigned inT = gamma & 8191u;
        unsigned row = inT >> 7;
        unsigned c   = inT & 127u;
        unsigned s   = tau >> 4, kt = tau & 15u;
        key = (row & 7u) << 4;
        unsigned baseBf = c ^ (key & 64u);
        srcF = x + (size_t)((row * 128u + s)) * 1024u
                 + kt * 64u + (baseBf >> 1);
        rowBase = beta - c;
    }
    // load 128 B of floats (8 x float4), pack 4 pieces, store with swizzled addr
    const f32x4* sv = reinterpret_cast<const f32x4*>(srcF);
    f32x4 f0 = sv[0], f1 = sv[1], f2 = sv[2], f3 = sv[3];
    f32x4 f4 = sv[4], f5 = sv[5], f6 = sv[6], f7 = sv[7];
    unsigned cTop = (beta < (unsigned)WS_X ? (beta & 16383u) : ((beta - (unsigned)WS_X) & 8191u)) & 64u;
    unsigned blockCol = cTop ^ (key & 64u);        // src-block logical col (64-aligned)
    #define PIECE(m, A, Bv) do { \
        u32x4 pk = { f2bf2(A.x, A.y), f2bf2(A.z, A.w), \
                     f2bf2(Bv.x, Bv.y), f2bf2(Bv.z, Bv.w) }; \
        *reinterpret_cast<u32x4*>(ws + rowBase + ((blockCol | (m)) ^ key)) = pk; \
    } while (0)
    PIECE(0u,  f0, f1);
    PIECE(16u, f2, f3);
    PIECE(32u, f4, f5);
    PIECE(48u, f6, f7);
    #undef PIECE
}

// ---- pass 2: paired GEMM, tile M=128 (2s x 64b) x N=128, BK=64, 8 waves
// (2 wm x 4 wn), each wave 64x32 = 4x2 fragments. Single-buffer 2-barrier
// loop (proven best); launch_bounds(512,6) caps VGPR ~85 -> 3 blocks/CU
// (24 waves) to probe whether staging rate scales past 16 waves/CU.
__global__ __launch_bounds__(512, 6) void moshi_gemm_n128(
    const unsigned char* __restrict__ ws, float* __restrict__ out) {
    __shared__ __align__(16) unsigned char lw[16384];   // 128(o) x 64(k) bf16, swizzled
    __shared__ __align__(16) unsigned char lx[16384];   // s0:64 rows + s1:64 rows

    // bijective XCD-chunk swizzle: grid 576 = 8 chunks of 72 (9 pairs x 8 nt)
    const int bid = (blockIdx.x & 7) * 72 + (blockIdx.x >> 3);
    const int pi = bid >> 3;
    const int nt = bid & 7;
    const int np = *reinterpret_cast<const int*>(ws + WS_P);
    if (pi >= np) return;   // block-uniform exit before any barrier
    const int4 pr = *reinterpret_cast<const int4*>(ws + WS_P + 16 + 16ull * pi);
    const int s0 = pr.x, s1 = pr.y, l = pr.z;

    const unsigned char* wt  = ws + WS_W + ((size_t)(l * 8 + nt) * 16) * 16384;
    const unsigned char* xt0 = ws + WS_X + (size_t)s0 * 16 * 8192;
    const unsigned char* xt1 = ws + WS_X + (size_t)s1 * 16 * 8192;

    const int tid = threadIdx.x, lane = tid & 63, wid = tid >> 6;
    const int wm = wid >> 2, wn = wid & 3;
    const int swz = (lane & 7) << 4;
    const int kb  = (lane >> 4) << 4;
    const int a_base = (wm * 64 + (lane & 15)) * 128 + kb;   // x rows
    const int b_base = (wn * 32 + (lane & 15)) * 128 + kb;   // W rows

    f32x4 acc[4][2];
    #pragma unroll
    for (int i = 0; i < 4; ++i)
        #pragma unroll
        for (int j = 0; j < 2; ++j) acc[i][j] = (f32x4)0.0f;

    #pragma unroll 1
    for (int kt = 0; kt < 16; ++kt) {
        __syncthreads();
        gload16(wt  + (size_t)kt * 16384 + tid * 16,        lw + tid * 16);
        gload16(wt  + (size_t)kt * 16384 + tid * 16 + 8192, lw + tid * 16 + 8192);
        gload16(xt0 + (size_t)kt * 8192  + tid * 16,        lx + tid * 16);
        gload16(xt1 + (size_t)kt * 8192  + tid * 16,        lx + tid * 16 + 8192);
        __syncthreads();
        #pragma unroll
        for (int kk = 0; kk < 2; ++kk) {
            bf16x8 af[4], bfr[2];
            #pragma unroll
            for (int mi = 0; mi < 4; ++mi)
                af[mi] = *reinterpret_cast<const bf16x8*>(
                    lx + (((a_base + kk * 64) ^ swz) + mi * 2048));
            #pragma unroll
            for (int ni = 0; ni < 2; ++ni)
                bfr[ni] = *reinterpret_cast<const bf16x8*>(
                    lw + (((b_base + kk * 64) ^ swz) + ni * 2048));
            #pragma unroll
            for (int mi = 0; mi < 4; ++mi)
                #pragma unroll
                for (int ni = 0; ni < 2; ++ni)
                    acc[mi][ni] = __builtin_amdgcn_mfma_f32_16x16x32_bf16(
                        af[mi], bfr[ni], acc[mi][ni], 0, 0, 0);
        }
    }

    // epilogue: C/D col = lane&15 (o), row = (lane>>4)*4 + reg (b)
    const int s_sel = wm ? s1 : s0;
    const int col0 = nt * 128 + wn * 32 + (lane & 15);
    const int r0 = (lane >> 4) << 2;
    #pragma unroll
    for (int mi = 0; mi < 4; ++mi)
        #pragma unroll
        for (int ni = 0; ni < 2; ++ni)
            #pragma unroll
            for (int r = 0; r < 4; ++r) {
                int b = mi * 16 + r0 + r;
                out[((size_t)b * S_ + s_sel) * O_ + col0 + ni * 16] = acc[mi][ni][r];
            }
}

// ---- fallback (round-1 kernel) if ws is too small ----
__global__ __launch_bounds__(256) void moshi_flin_fallback(
    const float* __restrict__ x, const int* __restrict__ lidx,
    const float* __restrict__ w, float* __restrict__ out) {
    __shared__ __align__(16) unsigned char lxs[64 * 128];
    __shared__ __align__(16) unsigned char lws[128 * 128];
    const int bid = blockIdx.x;
    const int s = bid >> 3, n0 = (bid & 7) << 7;
    const int tid = threadIdx.x, lane = tid & 63, wid = tid >> 6;
    const int idx = lidx[s];
    const float* wb = w + (size_t)idx * O_ * D_ + (size_t)n0 * D_;
    const float* xb = x + (size_t)s * D_;
    const int swz = (lane & 7) << 4;
    const int kb = (lane >> 4) << 4;
    const int a_base = (lane & 15) * 128 + kb;
    const int b_base = (wid * 32 + (lane & 15)) * 128 + kb;
    f32x4 acc[4][2];
    #pragma unroll
    for (int i = 0; i < 4; ++i)
        #pragma unroll
        for (int j = 0; j < 2; ++j) acc[i][j] = (f32x4)0.0f;
    for (int kt = 0; kt < D_; kt += 64) {
        __syncthreads();
        #pragma unroll
        for (int p = 0; p < 4; ++p) {
            int f = tid + p * 256, row = f >> 4, cc = (f & 15) << 2;
            const float4 v = *reinterpret_cast<const float4*>(
                xb + (size_t)row * (S_ * D_) + kt + cc);
            uint2 pk = { f2bf2(v.x, v.y), f2bf2(v.z, v.w) };
            *reinterpret_cast<uint2*>(&lxs[(row * 128 + cc * 2) ^ ((row & 7) << 4)]) = pk;
        }
        #pragma unroll
        for (int p = 0; p < 8; ++p) {
            int f = tid + p * 256, row = f >> 4, cc = (f & 15) << 2;
            const float4 v = *reinterpret_cast<const float4*>(
                wb + (size_t)row * D_ + kt + cc);
            uint2 pk = { f2bf2(v.x, v.y), f2bf2(v.z, v.w) };
            *reinterpret_cast<uint2*>(&lws[(row * 128 + cc * 2) ^ ((row & 7) << 4)]) = pk;
        }
        __syncthreads();
        #pragma unroll
        for (int kk = 0; kk < 2; ++kk) {
            bf16x8 af[4], bfr[2];
            #pragma unroll
            for (int mi = 0; mi < 4; ++mi)
                af[mi] = *reinterpret_cast<const bf16x8*>(
                    &lxs[(((a_base + kk * 64) ^ swz) + mi * 2048)]);
            #pragma unroll
            for (int ni = 0; ni < 2; ++ni)
                bfr[ni] = *reinterpret_cast<const bf16x8*>(
                    &lws[(((b_base + kk * 64) ^ swz) + ni * 2048)]);
            #pragma unroll
            for (int mi = 0; mi < 4; ++mi)
                #pragma unroll
                for (int ni = 0; ni < 2; ++ni)
                    acc[mi][ni] = __builtin_amdgcn_mfma_f32_16x16x32_bf16(
                        af[mi], bfr[ni], acc[mi][ni], 0, 0, 0);
        }
    }
    float* ob = out + (size_t)s * O_ + n0 + wid * 32 + (lane & 15);
    const int r0 = (lane >> 4) << 2;
    #pragma unroll
    for (int mi = 0; mi < 4; ++mi)
        #pragma unroll
        for (int ni = 0; ni < 2; ++ni)
            #pragma unroll
            for (int r = 0; r < 4; ++r) {
                int b = mi * 16 + r0 + r;
                ob[(size_t)b * (S_ * O_) + ni * 16] = acc[mi][ni][r];
            }
}

extern "C" void kernel_launch(void* const* d_in, const int* in_sizes, int n_in,
                              void* d_out, int out_size, void* d_ws, size_t ws_size,
                              hipStream_t stream) {
    const float* x  = (const float*)d_in[0];
    const int* lidx = (const int*)d_in[1];
    const float* w  = (const float*)d_in[2];
    float* out      = (float*)d_out;

    if (ws_size < WS_NEED) {
        moshi_flin_fallback<<<dim3(128 * 8), dim3(256), 0, stream>>>(x, lidx, w, out);
        return;
    }
    unsigned char* ws = (unsigned char*)d_ws;
    // 50331648 B of output / 64 B per thread = 786432 threads = 3072 blocks
    moshi_convert<<<dim3(3072), dim3(256), 0, stream>>>(x, w, lidx, ws);
    // 72 pair slots x 8 n-tiles, 512 threads
    moshi_gemm_n128<<<dim3(72 * 8), dim3(512), 0, stream>>>(ws, out);
}